// Round 2
// baseline (681.448 us; speedup 1.0000x reference)
//
#include <hip/hip_runtime.h>
#include <stdint.h>

#define B_ 1024
#define T_ 255
#define D_ 128
#define H_ 128
#define G_ 512   // 4*H

typedef float f32x4 __attribute__((ext_vector_type(4)));
typedef short s16x8 __attribute__((ext_vector_type(8)));

__device__ __forceinline__ unsigned short f32_bf16(float f){
  union { float f; unsigned u; } c; c.f = f;
  return (unsigned short)((c.u + 0x7fffu + ((c.u >> 16) & 1u)) >> 16);  // RNE
}
__device__ __forceinline__ float blo(unsigned u){ union{unsigned u;float f;}c; c.u = u << 16; return c.f; }
__device__ __forceinline__ float bhi(unsigned u){ union{unsigned u;float f;}c; c.u = u & 0xffff0000u; return c.f; }
__device__ __forceinline__ float sigm(float x){ return 1.f / (1.f + __expf(-x)); }
__device__ __forceinline__ float tanh_f(float x){ return 2.f / (1.f + __expf(-2.f * x)) - 1.f; }

// ---------------- Kernel 1: x_part + softmax over d -> attn[b][128] -------------
__global__ __launch_bounds__(256) void k_attn(const float* __restrict__ x,
                                              const float* __restrict__ Wa,
                                              float* __restrict__ attn){
  __shared__ float wxs[T_];
  __shared__ float part[256];
  __shared__ float xp[128];
  __shared__ float red[128];
  int tid = threadIdx.x, b = blockIdx.x;
  for (int t = tid; t < T_; t += 256) wxs[t] = Wa[2 * H_ + t];
  __syncthreads();
  int d = tid & 127, half = tid >> 7;
  const float* xb = x + (size_t)b * T_ * D_ + d;
  float acc = 0.f;
  for (int t = half; t < T_; t += 2) acc += xb[(size_t)t * D_] * wxs[t];
  part[tid] = acc;
  __syncthreads();
  if (tid < 128){ float v = part[tid] + part[tid + 128]; xp[tid] = v; red[tid] = v; }
  __syncthreads();
  for (int s = 64; s >= 1; s >>= 1){ if (tid < s) red[tid] = fmaxf(red[tid], red[tid + s]); __syncthreads(); }
  float mx = red[0];
  __syncthreads();
  float ev = 0.f;
  if (tid < 128){ ev = __expf(xp[tid] - mx); red[tid] = ev; }
  __syncthreads();
  for (int s = 64; s >= 1; s >>= 1){ if (tid < s) red[tid] += red[tid + s]; __syncthreads(); }
  float sm = red[0];
  if (tid < 128) attn[b * D_ + tid] = ev / sm;
}

// ---------------- Kernel 2: wx -> out0 ; G1 packed per-lane for k_rnn -----------
// grid 1024 = 64 b-groups (16 rows) x 16 t-chunks (16 t). 512 thr = 8 waves.
// wave w: d-slice [16w,16w+16), n-tiles {w, 8+w, 16+w, 24+w}  (gates i,f,g,o).
// G1 layout: [t][bg][w][lane] x 16 bf16 (32 B per lane, fully coalesced).
__global__ __launch_bounds__(512, 2) void k_gemm1(const float* __restrict__ x,
    const float* __restrict__ attn, const float* __restrict__ W_ih,
    const float* __restrict__ b_ih, const float* __restrict__ b_hh,
    float* __restrict__ out_w, uint4* __restrict__ g1q){
  int tid = threadIdx.x;
  int lane = tid & 63, w = tid >> 6;
  int l15 = lane & 15, lg = lane >> 4;
  int bx = blockIdx.x;
  int bg = bx & 63, tc = bx >> 6;
  int row0 = bg << 4;

  // W_ih B-fragments [kt][g], k-bijection k = kt*32 + lg*8 + j (same as A side)
  s16x8 bfr[4][4];
  #pragma unroll
  for (int g = 0; g < 4; g++){
    int n = g * 128 + w * 16 + l15;
    #pragma unroll
    for (int kt = 0; kt < 4; kt++){
      const float4* wp = (const float4*)(W_ih + n * D_ + kt * 32 + lg * 8);
      float4 w0 = wp[0], w1 = wp[1];
      s16x8 bb;
      bb[0]=(short)f32_bf16(w0.x); bb[1]=(short)f32_bf16(w0.y); bb[2]=(short)f32_bf16(w0.z); bb[3]=(short)f32_bf16(w0.w);
      bb[4]=(short)f32_bf16(w1.x); bb[5]=(short)f32_bf16(w1.y); bb[6]=(short)f32_bf16(w1.z); bb[7]=(short)f32_bf16(w1.w);
      bfr[kt][g] = bb;
    }
  }
  float bias[4];
  #pragma unroll
  for (int g = 0; g < 4; g++){
    int n = g * 128 + w * 16 + l15;
    bias[g] = b_ih[n] + b_hh[n];
  }
  // attn factors for the A (wx) build: row = row0 + l15
  float afr[4][8];
  #pragma unroll
  for (int kt = 0; kt < 4; kt++){
    const float4* ap = (const float4*)(attn + (row0 + l15) * D_ + kt * 32 + lg * 8);
    float4 a0 = ap[0], a1 = ap[1];
    afr[kt][0]=a0.x; afr[kt][1]=a0.y; afr[kt][2]=a0.z; afr[kt][3]=a0.w;
    afr[kt][4]=a1.x; afr[kt][5]=a1.y; afr[kt][6]=a1.z; afr[kt][7]=a1.w;
  }
  // coalesced wx stream: wave w writes rows {2w, 2w+1}
  int wrow = row0 + 2 * w + (lane >> 5);
  int wcol = (lane & 31) * 4;
  float4 awx = *(const float4*)(attn + wrow * D_ + wcol);
  const float4* xw = (const float4*)(x + ((size_t)wrow * T_ + (size_t)tc * 16) * D_ + wcol);
  float4*       ow = (float4*)(out_w + ((size_t)wrow * T_ + (size_t)tc * 16) * D_ + wcol);

  const float* xa = x + ((size_t)(row0 + l15) * T_ + (size_t)tc * 16) * D_;

  int tmax = T_ - tc * 16; if (tmax > 16) tmax = 16;
  for (int i = 0; i < tmax; i++){
    int t = tc * 16 + i;
    // A-frags: wx row l15
    s16x8 af[4];
    #pragma unroll
    for (int kt = 0; kt < 4; kt++){
      const float4* xp4 = (const float4*)(xa + (size_t)i * D_ + kt * 32 + lg * 8);
      float4 x0 = xp4[0], x1 = xp4[1];
      s16x8 a;
      a[0]=(short)f32_bf16(x0.x*afr[kt][0]); a[1]=(short)f32_bf16(x0.y*afr[kt][1]);
      a[2]=(short)f32_bf16(x0.z*afr[kt][2]); a[3]=(short)f32_bf16(x0.w*afr[kt][3]);
      a[4]=(short)f32_bf16(x1.x*afr[kt][4]); a[5]=(short)f32_bf16(x1.y*afr[kt][5]);
      a[6]=(short)f32_bf16(x1.z*afr[kt][6]); a[7]=(short)f32_bf16(x1.w*afr[kt][7]);
      af[kt] = a;
    }
    f32x4 ac0 = {0.f,0.f,0.f,0.f}, ac1 = ac0, ac2 = ac0, ac3 = ac0;
    #pragma unroll
    for (int kt = 0; kt < 4; kt++){
      ac0 = __builtin_amdgcn_mfma_f32_16x16x32_bf16(af[kt], bfr[kt][0], ac0, 0,0,0);
      ac1 = __builtin_amdgcn_mfma_f32_16x16x32_bf16(af[kt], bfr[kt][1], ac1, 0,0,0);
      ac2 = __builtin_amdgcn_mfma_f32_16x16x32_bf16(af[kt], bfr[kt][2], ac2, 0,0,0);
      ac3 = __builtin_amdgcn_mfma_f32_16x16x32_bf16(af[kt], bfr[kt][3], ac3, 0,0,0);
    }
    // wx stream (x lines are L1-hot from the A-build)
    float4 xv = xw[(size_t)i * 32];
    float4 wxv; wxv.x = xv.x*awx.x; wxv.y = xv.y*awx.y; wxv.z = xv.z*awx.z; wxv.w = xv.w*awx.w;
    ow[(size_t)i * 32] = wxv;
    // pack G1: dword 2r = (i,f), dword 2r+1 = (g,o), D-row = lg*4 + r
    unsigned dw[8];
    #pragma unroll
    for (int r = 0; r < 4; r++){
      float vi = ac0[r] + bias[0];
      float vf = ac1[r] + bias[1];
      float vg = ac2[r] + bias[2];
      float vo = ac3[r] + bias[3];
      dw[2*r]   = (unsigned)f32_bf16(vi) | ((unsigned)f32_bf16(vf) << 16);
      dw[2*r+1] = (unsigned)f32_bf16(vg) | ((unsigned)f32_bf16(vo) << 16);
    }
    size_t off = ((((size_t)t * 64 + bg) * 8 + w) * 64 + lane) * 2;
    g1q[off]     = make_uint4(dw[0], dw[1], dw[2], dw[3]);
    g1q[off + 1] = make_uint4(dw[4], dw[5], dw[6], dw[7]);
  }
}

// ---------------- Kernel 3: recurrence, 16 rows/block, lane-local cells ----------
// 64 blocks x 512 thr (8 waves). Wave w: d-slice [16w,16w+16), gates i/f/g/o in
// its own accumulators -> no gate exchange, 1 barrier/step. h double-buffered in LDS.
__global__ __launch_bounds__(512, 2) void k_rnn(const float* __restrict__ W_hh,
    const uint4* __restrict__ g1q, float* __restrict__ out_e){
  __shared__ char hl[8192];   // h bf16 [2][16][128], XOR-swizzled
  int tid = threadIdx.x;
  int lane = tid & 63, w = tid >> 6;
  int l15 = lane & 15, lg = lane >> 4;
  int bg = blockIdx.x;
  int row0 = bg << 4;
  int d = w * 16 + l15;

  // W_hh B-fragments [kt][g]
  s16x8 bfr[4][4];
  #pragma unroll
  for (int g = 0; g < 4; g++){
    int n = g * 128 + w * 16 + l15;
    #pragma unroll
    for (int kt = 0; kt < 4; kt++){
      const float4* wp = (const float4*)(W_hh + n * D_ + kt * 32 + lg * 8);
      float4 w0 = wp[0], w1 = wp[1];
      s16x8 bb;
      bb[0]=(short)f32_bf16(w0.x); bb[1]=(short)f32_bf16(w0.y); bb[2]=(short)f32_bf16(w0.z); bb[3]=(short)f32_bf16(w0.w);
      bb[4]=(short)f32_bf16(w1.x); bb[5]=(short)f32_bf16(w1.y); bb[6]=(short)f32_bf16(w1.z); bb[7]=(short)f32_bf16(w1.w);
      bfr[kt][g] = bb;
    }
  }
  // LDS addresses (both h buffers), swizzle byte ^= (row&7)<<4
  unsigned rd0[4], rd1[4];
  #pragma unroll
  for (int kt = 0; kt < 4; kt++){
    unsigned a = ((unsigned)(l15 * 256 + kt * 64 + lg * 16)) ^ ((unsigned)(l15 & 7) << 4);
    rd0[kt] = a; rd1[kt] = a + 4096;
  }
  unsigned wr0[4], wr1[4];
  #pragma unroll
  for (int r = 0; r < 4; r++){
    int row = lg * 4 + r;
    unsigned a = ((unsigned)(row * 256 + d * 2)) ^ ((unsigned)(row & 7) << 4);
    wr0[r] = a; wr1[r] = a + 4096;
  }
  float* op0 = out_e + (size_t)(row0 + lg * 4 + 0) * T_ * D_ + d;
  float* op1 = out_e + (size_t)(row0 + lg * 4 + 1) * T_ * D_ + d;
  float* op2 = out_e + (size_t)(row0 + lg * 4 + 2) * T_ * D_ + d;
  float* op3 = out_e + (size_t)(row0 + lg * 4 + 3) * T_ * D_ + d;
  float c0 = 0.f, c1 = 0.f, c2 = 0.f, c3 = 0.f;

  ((uint2*)hl)[tid] = make_uint2(0u, 0u);   // zero h buffer 0 (4 KB)

  size_t base = (((size_t)bg * 8 + w) * 64 + lane) * 2;   // + t*65536 (uint4 units)
  uint4 qa0 = g1q[base],          qa1 = g1q[base + 1];          // t=0
  uint4 qb0 = g1q[base + 65536],  qb1 = g1q[base + 65536 + 1];  // t=1
  __syncthreads();

#define RNN_STEP(Q0, Q1, RD, WR, OPIDX, TT) do {                                   \
    float gi0=blo(Q0.x), gf0=bhi(Q0.x), gg0=blo(Q0.y), go0=bhi(Q0.y);              \
    float gi1=blo(Q0.z), gf1=bhi(Q0.z), gg1=blo(Q0.w), go1=bhi(Q0.w);              \
    float gi2=blo(Q1.x), gf2=bhi(Q1.x), gg2=blo(Q1.y), go2=bhi(Q1.y);              \
    float gi3=blo(Q1.z), gf3=bhi(Q1.z), gg3=blo(Q1.w), go3=bhi(Q1.w);              \
    if ((TT) + 2 < T_){ size_t o = base + (size_t)((TT) + 2) * 65536;              \
      Q0 = g1q[o]; Q1 = g1q[o + 1]; }                                              \
    s16x8 aa[4];                                                                   \
    _Pragma("unroll")                                                              \
    for (int kt = 0; kt < 4; kt++) aa[kt] = *(const s16x8*)(hl + RD[kt]);          \
    f32x4 ac0 = {0.f,0.f,0.f,0.f}, ac1 = ac0, ac2 = ac0, ac3 = ac0;                \
    _Pragma("unroll")                                                              \
    for (int kt = 0; kt < 4; kt++){                                                \
      ac0 = __builtin_amdgcn_mfma_f32_16x16x32_bf16(aa[kt], bfr[kt][0], ac0,0,0,0);\
      ac1 = __builtin_amdgcn_mfma_f32_16x16x32_bf16(aa[kt], bfr[kt][1], ac1,0,0,0);\
      ac2 = __builtin_amdgcn_mfma_f32_16x16x32_bf16(aa[kt], bfr[kt][2], ac2,0,0,0);\
      ac3 = __builtin_amdgcn_mfma_f32_16x16x32_bf16(aa[kt], bfr[kt][3], ac3,0,0,0);\
    }                                                                              \
    { float ig = gi0 + ac0[0], fg = gf0 + ac1[0], gv = gg0 + ac2[0], og = go0 + ac3[0]; \
      float cn = sigm(fg) * c0 + sigm(ig) * tanh_f(gv);                            \
      float hn = sigm(og) * tanh_f(cn); c0 = cn;                                   \
      *op0 = hn; op0 += D_;                                                        \
      *(unsigned short*)(hl + WR[0]) = f32_bf16(hn); }                             \
    { float ig = gi1 + ac0[1], fg = gf1 + ac1[1], gv = gg1 + ac2[1], og = go1 + ac3[1]; \
      float cn = sigm(fg) * c1 + sigm(ig) * tanh_f(gv);                            \
      float hn = sigm(og) * tanh_f(cn); c1 = cn;                                   \
      *op1 = hn; op1 += D_;                                                        \
      *(unsigned short*)(hl + WR[1]) = f32_bf16(hn); }                             \
    { float ig = gi2 + ac0[2], fg = gf2 + ac1[2], gv = gg2 + ac2[2], og = go2 + ac3[2]; \
      float cn = sigm(fg) * c2 + sigm(ig) * tanh_f(gv);                            \
      float hn = sigm(og) * tanh_f(cn); c2 = cn;                                   \
      *op2 = hn; op2 += D_;                                                        \
      *(unsigned short*)(hl + WR[2]) = f32_bf16(hn); }                             \
    { float ig = gi3 + ac0[3], fg = gf3 + ac1[3], gv = gg3 + ac2[3], og = go3 + ac3[3]; \
      float cn = sigm(fg) * c3 + sigm(ig) * tanh_f(gv);                            \
      float hn = sigm(og) * tanh_f(cn); c3 = cn;                                   \
      *op3 = hn; op3 += D_;                                                        \
      *(unsigned short*)(hl + WR[3]) = f32_bf16(hn); }                             \
    __syncthreads();                                                               \
  } while (0)

  for (int t = 0; t < T_ - 1; t += 2){
    RNN_STEP(qa0, qa1, rd0, wr1, 0, t);       // even t: read buf0, write buf1
    RNN_STEP(qb0, qb1, rd1, wr0, 1, t + 1);   // odd  t: read buf1, write buf0
  }
  RNN_STEP(qa0, qa1, rd0, wr1, 0, T_ - 1);    // t = 254 (even)
#undef RNN_STEP
}

extern "C" void kernel_launch(void* const* d_in, const int* in_sizes, int n_in,
                              void* d_out, int out_size, void* d_ws, size_t ws_size,
                              hipStream_t stream) {
  (void)in_sizes; (void)n_in; (void)out_size;
  const float* x    = (const float*)d_in[0];
  const float* Wa   = (const float*)d_in[1];
  // d_in[2] = ba : dead (softmax shift invariance); Wh/Wc parts of Wa also dead
  const float* W_ih = (const float*)d_in[3];
  const float* W_hh = (const float*)d_in[4];
  const float* b_ih = (const float*)d_in[5];
  const float* b_hh = (const float*)d_in[6];
  float* out_w = (float*)d_out;
  float* out_e = out_w + (size_t)B_ * T_ * D_;
  float* attn = (float*)d_ws;
  uint4* g1q = (uint4*)((char*)d_ws + (1 << 20));
  size_t need = (size_t)(1 << 20) + (size_t)T_ * B_ * G_ * 2;
  if (ws_size < need) return;

  k_attn <<<B_, 256, 0, stream>>>(x, Wa, attn);
  k_gemm1<<<1024, 512, 0, stream>>>(x, attn, W_ih, b_ih, b_hh, out_w, g1q);
  k_rnn  <<<64, 512, 0, stream>>>(W_hh, g1q, out_e);
}

// Round 3
// 376.309 us; speedup vs baseline: 1.8109x; 1.8109x over previous
//
#include <hip/hip_runtime.h>
#include <stdint.h>

#define B_ 1024
#define T_ 255
#define D_ 128
#define G_ 512   // 4*H

typedef float f32x4 __attribute__((ext_vector_type(4)));
typedef short s16x8 __attribute__((ext_vector_type(8)));

__device__ __forceinline__ unsigned short f32_bf16(float f){
  union { float f; unsigned u; } c; c.f = f;
  return (unsigned short)((c.u + 0x7fffu + ((c.u >> 16) & 1u)) >> 16);  // RNE
}
// fast transcendentals: v_exp + v_rcp, no IEEE-division sequences
__device__ __forceinline__ float sigm_f(float x){
  return __builtin_amdgcn_rcpf(1.f + __expf(-x));
}
__device__ __forceinline__ float tanh_f2(float x){
  return fmaf(-2.f, __builtin_amdgcn_rcpf(1.f + __expf(2.f * x)), 1.f);
}

// ---------------- Kernel 1: softmax(x_part) ; out_w = attn*x ; wx bf16 ----------
// one block per b; x(b) staged in 130.5 KB dynamic LDS (single HBM read).
__global__ __launch_bounds__(512) void k_attn(const float* __restrict__ x,
    const float* __restrict__ Wa, float* __restrict__ out_w,
    uint2* __restrict__ wxq){
  extern __shared__ float4 xs4[];          // 8160 float4 = 130560 B
  __shared__ float wxs[256];
  __shared__ float part_s[16][128];
  __shared__ float red[128];
  __shared__ float attn_s[128];
  int tid = threadIdx.x, b = blockIdx.x;
  if (tid < T_) wxs[tid] = Wa[2 * D_ + tid];
  __syncthreads();
  const float4* xg = (const float4*)(x + (size_t)b * T_ * D_);
  float4 acc = {0.f, 0.f, 0.f, 0.f};
  for (int i = tid; i < 8160; i += 512){
    float4 v = xg[i];
    xs4[i] = v;
    float wt = wxs[i >> 5];
    acc.x += v.x * wt; acc.y += v.y * wt; acc.z += v.z * wt; acc.w += v.w * wt;
  }
  int d0 = (tid & 31) * 4, s = tid >> 5;
  *(float4*)&part_s[s][d0] = acc;
  __syncthreads();
  if (tid < 128){
    float v = 0.f;
    #pragma unroll
    for (int k = 0; k < 16; k++) v += part_s[k][tid];
    red[tid] = v; attn_s[tid] = v;        // stash x_part in attn_s
  }
  __syncthreads();
  for (int st = 64; st >= 1; st >>= 1){
    if (tid < st) red[tid] = fmaxf(red[tid], red[tid + st]);
    __syncthreads();
  }
  float mx = red[0];
  __syncthreads();
  float ev = 0.f;
  if (tid < 128){ ev = __expf(attn_s[tid] - mx); red[tid] = ev; }
  __syncthreads();
  for (int st = 64; st >= 1; st >>= 1){
    if (tid < st) red[tid] += red[tid + st];
    __syncthreads();
  }
  float sm = red[0];
  if (tid < 128) attn_s[tid] = ev / sm;   // attn_s(x_part) no longer read
  __syncthreads();
  float4 at = *(const float4*)&attn_s[d0];
  float4* owg = (float4*)(out_w + (size_t)b * T_ * D_);
  for (int i = tid; i < 8160; i += 512){
    float4 v = xs4[i];
    float4 wv; wv.x = v.x*at.x; wv.y = v.y*at.y; wv.z = v.z*at.z; wv.w = v.w*at.w;
    owg[i] = wv;
    int t = i >> 5;
    uint2 q;
    q.x = (unsigned)f32_bf16(wv.x) | ((unsigned)f32_bf16(wv.y) << 16);
    q.y = (unsigned)f32_bf16(wv.z) | ((unsigned)f32_bf16(wv.w) << 16);
    wxq[((size_t)t * B_ + b) * 32 + (i & 31)] = q;   // [t][b][d] bf16 row-major
  }
}

// ---------------- Kernel 2: fused recurrence. 64 blocks x 16 rows x 512 thr -----
// wave w owns d-slice [16w,16w+16) and all four gates for it (lane-local cells).
// gates = bias (acc-init) + wx@W_ih^T (MFMA, h-independent) + h@W_hh^T (MFMA).
__global__ __launch_bounds__(512, 2) void k_rnn(const float* __restrict__ W_ih,
    const float* __restrict__ W_hh, const float* __restrict__ b_ih,
    const float* __restrict__ b_hh, const unsigned short* __restrict__ wxb,
    float* __restrict__ out_e){
  __shared__ char hl[8192];   // h bf16 [2][16][128], XOR-swizzled
  int tid = threadIdx.x;
  int lane = tid & 63, w = tid >> 6;
  int l15 = lane & 15, lg = lane >> 4;
  int bg = blockIdx.x;
  int row0 = bg << 4;
  int d = w * 16 + l15;

  // B-fragments for W_ih and W_hh: [kt][gate], k = kt*32 + lg*8 + j
  s16x8 fih[4][4], fhh[4][4];
  float bias[4];
  #pragma unroll
  for (int g = 0; g < 4; g++){
    int n = g * 128 + w * 16 + l15;
    bias[g] = b_ih[n] + b_hh[n];
    #pragma unroll
    for (int kt = 0; kt < 4; kt++){
      const float4* p1 = (const float4*)(W_ih + n * D_ + kt * 32 + lg * 8);
      float4 a0 = p1[0], a1 = p1[1];
      s16x8 bb;
      bb[0]=(short)f32_bf16(a0.x); bb[1]=(short)f32_bf16(a0.y); bb[2]=(short)f32_bf16(a0.z); bb[3]=(short)f32_bf16(a0.w);
      bb[4]=(short)f32_bf16(a1.x); bb[5]=(short)f32_bf16(a1.y); bb[6]=(short)f32_bf16(a1.z); bb[7]=(short)f32_bf16(a1.w);
      fih[kt][g] = bb;
      const float4* p2 = (const float4*)(W_hh + n * D_ + kt * 32 + lg * 8);
      float4 c0v = p2[0], c1v = p2[1];
      s16x8 cc;
      cc[0]=(short)f32_bf16(c0v.x); cc[1]=(short)f32_bf16(c0v.y); cc[2]=(short)f32_bf16(c0v.z); cc[3]=(short)f32_bf16(c0v.w);
      cc[4]=(short)f32_bf16(c1v.x); cc[5]=(short)f32_bf16(c1v.y); cc[6]=(short)f32_bf16(c1v.z); cc[7]=(short)f32_bf16(c1v.w);
      fhh[kt][g] = cc;
    }
  }
  // h LDS addresses, swizzle byte ^= (row&7)<<4
  unsigned rd[4];
  #pragma unroll
  for (int kt = 0; kt < 4; kt++)
    rd[kt] = ((unsigned)(l15 * 256 + kt * 64 + lg * 16)) ^ ((unsigned)(l15 & 7) << 4);
  unsigned wr[4];
  #pragma unroll
  for (int r = 0; r < 4; r++){
    int row = lg * 4 + r;
    wr[r] = ((unsigned)(row * 256 + d * 2)) ^ ((unsigned)(row & 7) << 4);
  }
  float* op0 = out_e + (size_t)(row0 + lg * 4 + 0) * T_ * D_ + d;
  float* op1 = out_e + (size_t)(row0 + lg * 4 + 1) * T_ * D_ + d;
  float* op2 = out_e + (size_t)(row0 + lg * 4 + 2) * T_ * D_ + d;
  float* op3 = out_e + (size_t)(row0 + lg * 4 + 3) * T_ * D_ + d;
  float c0 = 0.f, c1 = 0.f, c2 = 0.f, c3 = 0.f;

  ((uint2*)hl)[tid] = make_uint2(0u, 0u);   // zero h buffer 0

  // wx A-frag stream: per-lane slice, 2-step register prefetch
  const unsigned short* wp = wxb + (size_t)(row0 + l15) * D_ + lg * 8;
  const size_t TS = (size_t)B_ * D_;        // elems per t
  s16x8 A0[4], A1[4];
  #pragma unroll
  for (int kt = 0; kt < 4; kt++) A0[kt] = *(const s16x8*)(wp + kt * 32);
  wp += TS;
  #pragma unroll
  for (int kt = 0; kt < 4; kt++) A1[kt] = *(const s16x8*)(wp + kt * 32);
  wp += TS;
  __syncthreads();

#define STEP(AR, RDOFF, WROFF, TT) do {                                             \
    s16x8 aa[4];                                                                    \
    _Pragma("unroll")                                                               \
    for (int kt = 0; kt < 4; kt++) aa[kt] = *(const s16x8*)(hl + rd[kt] + (RDOFF)); \
    f32x4 ac0 = {bias[0], bias[0], bias[0], bias[0]};                               \
    f32x4 ac1 = {bias[1], bias[1], bias[1], bias[1]};                               \
    f32x4 ac2 = {bias[2], bias[2], bias[2], bias[2]};                               \
    f32x4 ac3 = {bias[3], bias[3], bias[3], bias[3]};                               \
    _Pragma("unroll")                                                               \
    for (int kt = 0; kt < 4; kt++){                                                 \
      ac0 = __builtin_amdgcn_mfma_f32_16x16x32_bf16(AR[kt], fih[kt][0], ac0,0,0,0); \
      ac1 = __builtin_amdgcn_mfma_f32_16x16x32_bf16(AR[kt], fih[kt][1], ac1,0,0,0); \
      ac2 = __builtin_amdgcn_mfma_f32_16x16x32_bf16(AR[kt], fih[kt][2], ac2,0,0,0); \
      ac3 = __builtin_amdgcn_mfma_f32_16x16x32_bf16(AR[kt], fih[kt][3], ac3,0,0,0); \
    }                                                                               \
    if ((TT) + 2 < T_){                                                             \
      _Pragma("unroll")                                                             \
      for (int kt = 0; kt < 4; kt++) AR[kt] = *(const s16x8*)(wp + kt * 32);        \
      wp += TS;                                                                     \
    }                                                                               \
    _Pragma("unroll")                                                               \
    for (int kt = 0; kt < 4; kt++){                                                 \
      ac0 = __builtin_amdgcn_mfma_f32_16x16x32_bf16(aa[kt], fhh[kt][0], ac0,0,0,0); \
      ac1 = __builtin_amdgcn_mfma_f32_16x16x32_bf16(aa[kt], fhh[kt][1], ac1,0,0,0); \
      ac2 = __builtin_amdgcn_mfma_f32_16x16x32_bf16(aa[kt], fhh[kt][2], ac2,0,0,0); \
      ac3 = __builtin_amdgcn_mfma_f32_16x16x32_bf16(aa[kt], fhh[kt][3], ac3,0,0,0); \
    }                                                                               \
    { float cn = fmaf(sigm_f(ac1[0]), c0, sigm_f(ac0[0]) * tanh_f2(ac2[0]));        \
      float hn = sigm_f(ac3[0]) * tanh_f2(cn); c0 = cn;                             \
      *op0 = hn; op0 += D_;                                                         \
      *(unsigned short*)(hl + wr[0] + (WROFF)) = f32_bf16(hn); }                    \
    { float cn = fmaf(sigm_f(ac1[1]), c1, sigm_f(ac0[1]) * tanh_f2(ac2[1]));        \
      float hn = sigm_f(ac3[1]) * tanh_f2(cn); c1 = cn;                             \
      *op1 = hn; op1 += D_;                                                         \
      *(unsigned short*)(hl + wr[1] + (WROFF)) = f32_bf16(hn); }                    \
    { float cn = fmaf(sigm_f(ac1[2]), c2, sigm_f(ac0[2]) * tanh_f2(ac2[2]));        \
      float hn = sigm_f(ac3[2]) * tanh_f2(cn); c2 = cn;                             \
      *op2 = hn; op2 += D_;                                                         \
      *(unsigned short*)(hl + wr[2] + (WROFF)) = f32_bf16(hn); }                    \
    { float cn = fmaf(sigm_f(ac1[3]), c3, sigm_f(ac0[3]) * tanh_f2(ac2[3]));        \
      float hn = sigm_f(ac3[3]) * tanh_f2(cn); c3 = cn;                             \
      *op3 = hn; op3 += D_;                                                         \
      *(unsigned short*)(hl + wr[3] + (WROFF)) = f32_bf16(hn); }                    \
    __syncthreads();                                                                \
  } while (0)

  for (int t = 0; t < T_ - 1; t += 2){
    STEP(A0, 0, 4096, t);         // even t: read h buf0, write buf1
    STEP(A1, 4096, 0, t + 1);     // odd  t: read buf1, write buf0
  }
  STEP(A0, 0, 4096, T_ - 1);      // t = 254 (even)
#undef STEP
}

extern "C" void kernel_launch(void* const* d_in, const int* in_sizes, int n_in,
                              void* d_out, int out_size, void* d_ws, size_t ws_size,
                              hipStream_t stream) {
  (void)in_sizes; (void)n_in; (void)out_size;
  const float* x    = (const float*)d_in[0];
  const float* Wa   = (const float*)d_in[1];
  // d_in[2] = ba : dead (softmax shift invariance); Wh/Wc parts of Wa also dead
  const float* W_ih = (const float*)d_in[3];
  const float* W_hh = (const float*)d_in[4];
  const float* b_ih = (const float*)d_in[5];
  const float* b_hh = (const float*)d_in[6];
  float* out_w = (float*)d_out;
  float* out_e = out_w + (size_t)B_ * T_ * D_;
  unsigned short* wxb = (unsigned short*)d_ws;   // [t][b][d] bf16, 66.8 MB
  size_t need = (size_t)T_ * B_ * D_ * 2;
  if (ws_size < need) return;

  k_attn<<<B_, 512, 130560, stream>>>(x, Wa, out_w, (uint2*)wxb);
  k_rnn <<<64, 512, 0, stream>>>(W_ih, W_hh, b_ih, b_hh, wxb, out_e);
}

// Round 4
// 290.759 us; speedup vs baseline: 2.3437x; 1.2942x over previous
//
#include <hip/hip_runtime.h>
#include <stdint.h>

#define B_ 1024
#define T_ 255
#define D_ 128
#define G_ 512   // 4*H

typedef float f32x4 __attribute__((ext_vector_type(4)));
typedef short s16x8 __attribute__((ext_vector_type(8)));

__device__ __forceinline__ unsigned short f32_bf16(float f){
  union { float f; unsigned u; } c; c.f = f;
  return (unsigned short)((c.u + 0x7fffu + ((c.u >> 16) & 1u)) >> 16);  // RNE
}
// fast transcendentals: v_exp + v_rcp, no IEEE-division sequences
__device__ __forceinline__ float sigm_f(float x){
  return __builtin_amdgcn_rcpf(1.f + __expf(-x));
}
__device__ __forceinline__ float tanh_f2(float x){
  return fmaf(-2.f, __builtin_amdgcn_rcpf(1.f + __expf(2.f * x)), 1.f);
}

// ---------------- Kernel 1: softmax(x_part) ; out_w = attn*x ; wx bf16 ----------
// one block per b; x(b) staged in 130.5 KB dynamic LDS (single HBM read).
__global__ __launch_bounds__(512) void k_attn(const float* __restrict__ x,
    const float* __restrict__ Wa, float* __restrict__ out_w,
    uint2* __restrict__ wxq){
  extern __shared__ float4 xs4[];          // 8160 float4 = 130560 B
  __shared__ float wxs[256];
  __shared__ float part_s[16][128];
  __shared__ float red[128];
  __shared__ float attn_s[128];
  int tid = threadIdx.x, b = blockIdx.x;
  if (tid < T_) wxs[tid] = Wa[2 * D_ + tid];
  __syncthreads();
  const float4* xg = (const float4*)(x + (size_t)b * T_ * D_);
  float4 acc = {0.f, 0.f, 0.f, 0.f};
  for (int i = tid; i < 8160; i += 512){
    float4 v = xg[i];
    xs4[i] = v;
    float wt = wxs[i >> 5];
    acc.x += v.x * wt; acc.y += v.y * wt; acc.z += v.z * wt; acc.w += v.w * wt;
  }
  int d0 = (tid & 31) * 4, s = tid >> 5;
  *(float4*)&part_s[s][d0] = acc;
  __syncthreads();
  if (tid < 128){
    float v = 0.f;
    #pragma unroll
    for (int k = 0; k < 16; k++) v += part_s[k][tid];
    red[tid] = v; attn_s[tid] = v;        // stash x_part in attn_s
  }
  __syncthreads();
  for (int st = 64; st >= 1; st >>= 1){
    if (tid < st) red[tid] = fmaxf(red[tid], red[tid + st]);
    __syncthreads();
  }
  float mx = red[0];
  __syncthreads();
  float ev = 0.f;
  if (tid < 128){ ev = __expf(attn_s[tid] - mx); red[tid] = ev; }
  __syncthreads();
  for (int st = 64; st >= 1; st >>= 1){
    if (tid < st) red[tid] += red[tid + st];
    __syncthreads();
  }
  float sm = red[0];
  if (tid < 128) attn_s[tid] = ev / sm;
  __syncthreads();
  float4 at = *(const float4*)&attn_s[d0];
  float4* owg = (float4*)(out_w + (size_t)b * T_ * D_);
  for (int i = tid; i < 8160; i += 512){
    float4 v = xs4[i];
    float4 wv; wv.x = v.x*at.x; wv.y = v.y*at.y; wv.z = v.z*at.z; wv.w = v.w*at.w;
    owg[i] = wv;
    int t = i >> 5;
    uint2 q;
    q.x = (unsigned)f32_bf16(wv.x) | ((unsigned)f32_bf16(wv.y) << 16);
    q.y = (unsigned)f32_bf16(wv.z) | ((unsigned)f32_bf16(wv.w) << 16);
    wxq[((size_t)t * B_ + b) * 32 + (i & 31)] = q;   // [t][b][d] bf16 row-major
  }
}

// ---------------- Kernel 2: fused recurrence. 256 blocks x 4 rows x 512 thr -----
// Batch row j is placed at A M-row 4j (lane l15 reads row l15>>2, replicated).
// With C layout row=lg*4+r, lane group lg holds batch row lg at acc[0]:
// every lane owns exactly ONE cell (row=lg, d=w*16+l15) -> 10 trans/lane/step.
__global__ __launch_bounds__(512, 2) void k_rnn(const float* __restrict__ W_ih,
    const float* __restrict__ W_hh, const float* __restrict__ b_ih,
    const float* __restrict__ b_hh, const unsigned short* __restrict__ wxb,
    float* __restrict__ out_e){
  __shared__ char hl[2048];   // h bf16 [2][4][128], byte ^= (row<<4) swizzle
  int tid = threadIdx.x;
  int lane = tid & 63, w = tid >> 6;
  int l15 = lane & 15, lg = lane >> 4;
  int bg = blockIdx.x;
  int row0 = bg << 2;
  int d = w * 16 + l15;
  int hr = l15 >> 2;          // h/wx row this lane reads (x4 replication)

  // B-fragments for W_ih and W_hh: [kt][gate], k = kt*32 + lg*8 + j
  s16x8 fih[4][4], fhh[4][4];
  float bias[4];
  #pragma unroll
  for (int g = 0; g < 4; g++){
    int n = g * 128 + w * 16 + l15;
    bias[g] = b_ih[n] + b_hh[n];
    #pragma unroll
    for (int kt = 0; kt < 4; kt++){
      const float4* p1 = (const float4*)(W_ih + n * D_ + kt * 32 + lg * 8);
      float4 a0 = p1[0], a1 = p1[1];
      s16x8 bb;
      bb[0]=(short)f32_bf16(a0.x); bb[1]=(short)f32_bf16(a0.y); bb[2]=(short)f32_bf16(a0.z); bb[3]=(short)f32_bf16(a0.w);
      bb[4]=(short)f32_bf16(a1.x); bb[5]=(short)f32_bf16(a1.y); bb[6]=(short)f32_bf16(a1.z); bb[7]=(short)f32_bf16(a1.w);
      fih[kt][g] = bb;
      const float4* p2 = (const float4*)(W_hh + n * D_ + kt * 32 + lg * 8);
      float4 c0v = p2[0], c1v = p2[1];
      s16x8 cc;
      cc[0]=(short)f32_bf16(c0v.x); cc[1]=(short)f32_bf16(c0v.y); cc[2]=(short)f32_bf16(c0v.z); cc[3]=(short)f32_bf16(c0v.w);
      cc[4]=(short)f32_bf16(c1v.x); cc[5]=(short)f32_bf16(c1v.y); cc[6]=(short)f32_bf16(c1v.z); cc[7]=(short)f32_bf16(c1v.w);
      fhh[kt][g] = cc;
    }
  }
  // h LDS addresses: layout [row][d] bf16 (256 B/row), swizzle byte ^= row<<4
  unsigned rd[4];
  #pragma unroll
  for (int kt = 0; kt < 4; kt++)
    rd[kt] = ((unsigned)(hr * 256 + kt * 64 + lg * 16)) ^ ((unsigned)hr << 4);
  unsigned wr_ = ((unsigned)(lg * 256 + d * 2)) ^ ((unsigned)lg << 4);

  float* op = out_e + (size_t)(row0 + lg) * T_ * D_ + d;
  float cst = 0.f;
  if (tid < 256) ((unsigned*)hl)[tid] = 0u;   // zero h buffer 0 (1 KB)

  // wx A-frag stream: lane reads row (row0+hr), k-slice lg*8 in each kt; 2-step prefetch
  const unsigned short* wp = wxb + (size_t)(row0 + hr) * D_ + lg * 8;
  const size_t TS = (size_t)B_ * D_;          // elems per t
  s16x8 A0[4], A1[4];
  #pragma unroll
  for (int kt = 0; kt < 4; kt++) A0[kt] = *(const s16x8*)(wp + kt * 32);
  wp += TS;
  #pragma unroll
  for (int kt = 0; kt < 4; kt++) A1[kt] = *(const s16x8*)(wp + kt * 32);
  wp += TS;
  __syncthreads();

#define STEP(AR, RDOFF, WROFF, TT) do {                                             \
    s16x8 aa[4];                                                                    \
    _Pragma("unroll")                                                               \
    for (int kt = 0; kt < 4; kt++) aa[kt] = *(const s16x8*)(hl + rd[kt] + (RDOFF)); \
    f32x4 ac0 = {bias[0], bias[0], bias[0], bias[0]};                               \
    f32x4 ac1 = {bias[1], bias[1], bias[1], bias[1]};                               \
    f32x4 ac2 = {bias[2], bias[2], bias[2], bias[2]};                               \
    f32x4 ac3 = {bias[3], bias[3], bias[3], bias[3]};                               \
    _Pragma("unroll")                                                               \
    for (int kt = 0; kt < 4; kt++){                                                 \
      ac0 = __builtin_amdgcn_mfma_f32_16x16x32_bf16(AR[kt], fih[kt][0], ac0,0,0,0); \
      ac1 = __builtin_amdgcn_mfma_f32_16x16x32_bf16(AR[kt], fih[kt][1], ac1,0,0,0); \
      ac2 = __builtin_amdgcn_mfma_f32_16x16x32_bf16(AR[kt], fih[kt][2], ac2,0,0,0); \
      ac3 = __builtin_amdgcn_mfma_f32_16x16x32_bf16(AR[kt], fih[kt][3], ac3,0,0,0); \
    }                                                                               \
    if ((TT) + 2 < T_){                                                             \
      _Pragma("unroll")                                                             \
      for (int kt = 0; kt < 4; kt++) AR[kt] = *(const s16x8*)(wp + kt * 32);        \
      wp += TS;                                                                     \
    }                                                                               \
    _Pragma("unroll")                                                               \
    for (int kt = 0; kt < 4; kt++){                                                 \
      ac0 = __builtin_amdgcn_mfma_f32_16x16x32_bf16(aa[kt], fhh[kt][0], ac0,0,0,0); \
      ac1 = __builtin_amdgcn_mfma_f32_16x16x32_bf16(aa[kt], fhh[kt][1], ac1,0,0,0); \
      ac2 = __builtin_amdgcn_mfma_f32_16x16x32_bf16(aa[kt], fhh[kt][2], ac2,0,0,0); \
      ac3 = __builtin_amdgcn_mfma_f32_16x16x32_bf16(aa[kt], fhh[kt][3], ac3,0,0,0); \
    }                                                                               \
    { float cn = fmaf(sigm_f(ac1[0]), cst, sigm_f(ac0[0]) * tanh_f2(ac2[0]));       \
      float hn = sigm_f(ac3[0]) * tanh_f2(cn); cst = cn;                            \
      *op = hn; op += D_;                                                           \
      *(unsigned short*)(hl + wr_ + (WROFF)) = f32_bf16(hn); }                      \
    __syncthreads();                                                                \
  } while (0)

  for (int t = 0; t < T_ - 1; t += 2){
    STEP(A0, 0, 1024, t);         // even t: read h buf0, write buf1
    STEP(A1, 1024, 0, t + 1);     // odd  t: read buf1, write buf0
  }
  STEP(A0, 0, 1024, T_ - 1);      // t = 254 (even)
#undef STEP
}

extern "C" void kernel_launch(void* const* d_in, const int* in_sizes, int n_in,
                              void* d_out, int out_size, void* d_ws, size_t ws_size,
                              hipStream_t stream) {
  (void)in_sizes; (void)n_in; (void)out_size;
  const float* x    = (const float*)d_in[0];
  const float* Wa   = (const float*)d_in[1];
  // d_in[2] = ba : dead (softmax shift invariance); Wh/Wc parts of Wa also dead
  const float* W_ih = (const float*)d_in[3];
  const float* W_hh = (const float*)d_in[4];
  const float* b_ih = (const float*)d_in[5];
  const float* b_hh = (const float*)d_in[6];
  float* out_w = (float*)d_out;
  float* out_e = out_w + (size_t)B_ * T_ * D_;
  unsigned short* wxb = (unsigned short*)d_ws;   // [t][b][d] bf16, 66.8 MB
  size_t need = (size_t)T_ * B_ * D_ * 2;
  if (ws_size < need) return;

  k_attn<<<B_, 512, 130560, stream>>>(x, Wa, out_w, (uint2*)wxb);
  k_rnn <<<256, 512, 0, stream>>>(W_ih, W_hh, b_ih, b_hh, wxb, out_e);
}